// Round 7
// baseline (650.927 us; speedup 1.0000x reference)
//
#include <hip/hip_runtime.h>
#include <hip/hip_bf16.h>

#define B_  2
#define S_  2048
#define D_  2048
#define H_  16
#define DH_ 128
#define M_  (B_*S_)   // 4096

typedef __hip_bfloat16 bf16;
typedef float v4f __attribute__((ext_vector_type(4)));
typedef short v8s __attribute__((ext_vector_type(8)));

__device__ __forceinline__ short f2s(float x) {
  bf16 h = __float2bfloat16(x);
  return *reinterpret_cast<const short*>(&h);
}
// load 8 contiguous elems as bf16 bits (converting if f32)
__device__ __forceinline__ v8s ld8(const float* p) {
  v4f a = *reinterpret_cast<const v4f*>(p);
  v4f b = *reinterpret_cast<const v4f*>(p + 4);
  v8s r = { f2s(a[0]), f2s(a[1]), f2s(a[2]), f2s(a[3]),
            f2s(b[0]), f2s(b[1]), f2s(b[2]), f2s(b[3]) };
  return r;
}
__device__ __forceinline__ v8s ld8(const bf16* p) {
  return *reinterpret_cast<const v8s*>(p);
}
__device__ __forceinline__ void store_out(bf16* p, float v)  { *p = __float2bfloat16(v); }
__device__ __forceinline__ void store_out(float* p, float v) { *p = v; }

// C = A @ W^T + bias ; A [M,K] row-major (TA elems), W [N,K] row-major f32.
// MODE 0: Q -> [B,H,S,dh] scaled by 1/sqrt(dh)*log2(e)
// MODE 1: K -> [B,H,S,dh]
// MODE 2: V -> [B,H,dh,S]  (transposed for PV fragment loads)
// MODE 3: plain [M,N]   (f32 out for the final projection)
template <int MODE, typename TA, typename TOUT>
__global__ __launch_bounds__(256) void gemm_bt(const TA* __restrict__ A,
                                               const float* __restrict__ W,
                                               const float* __restrict__ bias,
                                               TOUT* __restrict__ out) {
  __shared__ __align__(16) bf16 As[128 * 32];
  __shared__ __align__(16) bf16 Bs[128 * 32];
  const int tid  = threadIdx.x;
  const int lane = tid & 63, wave = tid >> 6;
  const int wm = wave >> 1, wn = wave & 1;
  const int quad = lane >> 4, l16 = lane & 15;
  const int bm = blockIdx.y * 128, bn = blockIdx.x * 128;

  const int srow = tid >> 2;          // 0..63
  const int sch  = (tid & 3) * 8;     // elem offset within 32-elem row
  const TA*    aptr = A + (size_t)(bm + srow) * D_ + sch;
  const float* bptr = W + (size_t)(bn + srow) * D_ + sch;

  v4f acc[4][4] = {};
  for (int k0 = 0; k0 < D_; k0 += 32) {
    v8s a0 = ld8(aptr + k0);
    v8s a1 = ld8(aptr + (size_t)64 * D_ + k0);
    v8s b0 = ld8(bptr + k0);
    v8s b1 = ld8(bptr + (size_t)64 * D_ + k0);
    *reinterpret_cast<v8s*>(&As[srow * 32 + sch])        = a0;
    *reinterpret_cast<v8s*>(&As[(64 + srow) * 32 + sch]) = a1;
    *reinterpret_cast<v8s*>(&Bs[srow * 32 + sch])        = b0;
    *reinterpret_cast<v8s*>(&Bs[(64 + srow) * 32 + sch]) = b1;
    __syncthreads();
    v8s af[4], bfr[4];
#pragma unroll
    for (int mi = 0; mi < 4; ++mi)
      af[mi] = *reinterpret_cast<const v8s*>(&As[(wm * 64 + mi * 16 + l16) * 32 + quad * 8]);
#pragma unroll
    for (int ni = 0; ni < 4; ++ni)
      bfr[ni] = *reinterpret_cast<const v8s*>(&Bs[(wn * 64 + ni * 16 + l16) * 32 + quad * 8]);
#pragma unroll
    for (int mi = 0; mi < 4; ++mi)
#pragma unroll
      for (int ni = 0; ni < 4; ++ni)
        acc[mi][ni] = __builtin_amdgcn_mfma_f32_16x16x32_bf16(af[mi], bfr[ni], acc[mi][ni], 0, 0, 0);
    __syncthreads();
  }

  constexpr float QSCALE = 0.12752003912f;  // 1/sqrt(128) * log2(e)
#pragma unroll
  for (int ni = 0; ni < 4; ++ni) {
    const int n = bn + wn * 64 + ni * 16 + l16;
    const float bv = bias[n];
#pragma unroll
    for (int mi = 0; mi < 4; ++mi) {
      const int m0 = bm + wm * 64 + mi * 16 + quad * 4;
#pragma unroll
      for (int r = 0; r < 4; ++r) {
        const int m = m0 + r;           // row m: (b,s). col n: (h,d)
        float v = acc[mi][ni][r] + bv;
        size_t idx;
        if (MODE == 0 || MODE == 1) {
          if (MODE == 0) v *= QSCALE;
          int b = m >> 11, s = m & (S_ - 1);
          int h = n >> 7,  d = n & (DH_ - 1);
          idx = ((size_t)(b * H_ + h) * S_ + s) * DH_ + d;
        } else if (MODE == 2) {
          int b = m >> 11, s = m & (S_ - 1);
          int h = n >> 7,  d = n & (DH_ - 1);
          idx = ((size_t)(b * H_ + h) * DH_ + d) * S_ + s;
        } else {
          idx = (size_t)m * D_ + n;
        }
        store_out(out + idx, v);
      }
    }
  }
}

// Flash attention, causal. Q/K: [B,H,S,dh], Vt: [B,H,dh,S] (all bf16). Out: [B,S,D] bf16.
// Block = 64 Q rows (4 waves x 16 rows), K-tile = 64 keys.
#define KSTR 136   // Ks row stride (elems): 272 B -> 16B-aligned rows, 2-way banks (free)
#define VSTR 72    // Vs row stride (elems): 144 B
__global__ __launch_bounds__(256) void attn_fused(const bf16* __restrict__ Q,
                                                  const bf16* __restrict__ K,
                                                  const bf16* __restrict__ Vt,
                                                  bf16* __restrict__ Oa) {
  __shared__ __align__(16) bf16 Ks[64 * KSTR];   // [key][d], padded
  __shared__ __align__(16) bf16 Vs[128 * VSTR];  // [d][key], padded
  __shared__ __align__(16) bf16 Ps[4][16 * 72];  // per-wave P, padded stride 72
  const int tid  = threadIdx.x;
  const int lane = tid & 63, wave = tid >> 6;
  const int quad = lane >> 4, l16 = lane & 15;
  const int qt = blockIdx.x, bh = blockIdx.y;
  const int b = bh >> 4, h = bh & 15;
  const bf16* Qh = Q  + (size_t)bh * S_ * DH_;
  const bf16* Kh = K  + (size_t)bh * S_ * DH_;
  const bf16* Vh = Vt + (size_t)bh * DH_ * S_;

  const int qrow0 = qt * 64 + wave * 16;
  v8s qf[4];
#pragma unroll
  for (int kk = 0; kk < 4; ++kk)
    qf[kk] = *reinterpret_cast<const v8s*>(&Qh[(size_t)(qrow0 + l16) * DH_ + kk * 32 + quad * 8]);

  v4f acc_o[8] = {};
  float m_i[4], l_i[4];
#pragma unroll
  for (int r = 0; r < 4; ++r) { m_i[r] = -1.0e30f; l_i[r] = 0.f; }

  for (int kt = 0; kt <= qt; ++kt) {
    const int kbase = kt * 64;
#pragma unroll
    for (int c = 0; c < 4; ++c) {
      int kr = c * 16 + (tid >> 4);     // 16 K-rows per round
      *reinterpret_cast<v8s*>(&Ks[kr * KSTR + (tid & 15) * 8]) =
          *reinterpret_cast<const v8s*>(&Kh[(size_t)(kbase + kr) * DH_ + (tid & 15) * 8]);
      int vr2 = c * 32 + (tid >> 3);    // 32 V-rows per round
      *reinterpret_cast<v8s*>(&Vs[vr2 * VSTR + (tid & 7) * 8]) =
          *reinterpret_cast<const v8s*>(&Vh[(size_t)vr2 * S_ + kbase + (tid & 7) * 8]);
    }
    __syncthreads();

    // S = Q K^T (Q pre-scaled by 1/sqrt(dh)*log2e)
    v4f sc[4];
#pragma unroll
    for (int nt = 0; nt < 4; ++nt) {
      v4f a = {};
#pragma unroll
      for (int kk = 0; kk < 4; ++kk) {
        v8s kf = *reinterpret_cast<const v8s*>(&Ks[(nt * 16 + l16) * KSTR + (kk * 4 + quad) * 8]);
        a = __builtin_amdgcn_mfma_f32_16x16x32_bf16(qf[kk], kf, a, 0, 0, 0);
      }
      sc[nt] = a;
    }
    if (kt == qt) {   // causal mask only on the diagonal tile
#pragma unroll
      for (int nt = 0; nt < 4; ++nt)
#pragma unroll
        for (int r = 0; r < 4; ++r) {
          int kc = kbase + nt * 16 + l16;
          int qr = qrow0 + quad * 4 + r;
          if (kc > qr) sc[nt][r] = -1.0e30f;
        }
    }
    // online softmax; C-layout: row = quad*4 + r, col = nt*16 + l16
#pragma unroll
    for (int r = 0; r < 4; ++r) {
      float mx = fmaxf(fmaxf(sc[0][r], sc[1][r]), fmaxf(sc[2][r], sc[3][r]));
      mx = fmaxf(mx, __shfl_xor(mx, 1));
      mx = fmaxf(mx, __shfl_xor(mx, 2));
      mx = fmaxf(mx, __shfl_xor(mx, 4));
      mx = fmaxf(mx, __shfl_xor(mx, 8));
      float mnew = fmaxf(mx, m_i[r]);
      float alpha = exp2f(m_i[r] - mnew);
      m_i[r] = mnew;
      l_i[r] *= alpha;
#pragma unroll
      for (int nt8 = 0; nt8 < 8; ++nt8) acc_o[nt8][r] *= alpha;
      float s0 = exp2f(sc[0][r] - mnew);
      float s1 = exp2f(sc[1][r] - mnew);
      float s2 = exp2f(sc[2][r] - mnew);
      float s3 = exp2f(sc[3][r] - mnew);
      sc[0][r] = s0; sc[1][r] = s1; sc[2][r] = s2; sc[3][r] = s3;
      float t = s0 + s1 + s2 + s3;
      t += __shfl_xor(t, 1); t += __shfl_xor(t, 2);
      t += __shfl_xor(t, 4); t += __shfl_xor(t, 8);
      l_i[r] += t;
    }
    // P: C-layout regs -> LDS (bf16) -> A-layout frags
#pragma unroll
    for (int nt = 0; nt < 4; ++nt)
#pragma unroll
      for (int r = 0; r < 4; ++r)
        Ps[wave][(quad * 4 + r) * 72 + nt * 16 + l16] = __float2bfloat16(sc[nt][r]);
    __syncthreads();
    // O += P V
#pragma unroll
    for (int kk2 = 0; kk2 < 2; ++kk2) {
      v8s pf = *reinterpret_cast<const v8s*>(&Ps[wave][l16 * 72 + kk2 * 32 + quad * 8]);
#pragma unroll
      for (int nt8 = 0; nt8 < 8; ++nt8) {
        v8s vf = *reinterpret_cast<const v8s*>(&Vs[(nt8 * 16 + l16) * VSTR + (kk2 * 4 + quad) * 8]);
        acc_o[nt8] = __builtin_amdgcn_mfma_f32_16x16x32_bf16(pf, vf, acc_o[nt8], 0, 0, 0);
      }
    }
    __syncthreads();
  }

#pragma unroll
  for (int r = 0; r < 4; ++r) {
    const float inv = 1.0f / l_i[r];
    const int srow = qrow0 + quad * 4 + r;
#pragma unroll
    for (int nt8 = 0; nt8 < 8; ++nt8)
      Oa[((size_t)b * S_ + srow) * D_ + h * DH_ + nt8 * 16 + l16] =
          __float2bfloat16(acc_o[nt8][r] * inv);
  }
}

extern "C" void kernel_launch(void* const* d_in, const int* in_sizes, int n_in,
                              void* d_out, int out_size, void* d_ws, size_t ws_size,
                              hipStream_t stream) {
  // Canary: all-zero output (absmax exactly 3.5625) signals a tripped assumption.
  if (n_in != 9 ||
      in_sizes[0] != M_ * D_ ||
      in_sizes[1] != D_ * D_ || in_sizes[2] != D_ ||
      in_sizes[3] != D_ * D_ || in_sizes[4] != D_ ||
      in_sizes[5] != D_ * D_ || in_sizes[6] != D_ ||
      in_sizes[7] != D_ * D_ || in_sizes[8] != D_ ||
      out_size != M_ * D_)
    return;

  const float* x  = (const float*)d_in[0];
  const float* Wq = (const float*)d_in[1];
  const float* bq = (const float*)d_in[2];
  const float* Wk = (const float*)d_in[3];
  const float* bk = (const float*)d_in[4];
  const float* Wv = (const float*)d_in[5];
  const float* bv = (const float*)d_in[6];
  const float* Wo = (const float*)d_in[7];
  const float* bo = (const float*)d_in[8];
  float* out = (float*)d_out;   // OUTPUT IS FLOAT32 (reference output dtype)

  const size_t NT = (size_t)M_ * D_;   // 8388608 elems per tensor
  // Q (bf16, 16.8 MB) parks in d_out (f32 buffer, 33.6 MB): dead before the
  // final GEMM overwrites d_out. ws holds K, Vt, attn-out (48 MB, proven OK).
  bf16* qws = (bf16*)d_out;
  bf16* kws = (bf16*)d_ws;
  bf16* vtw = kws + NT;
  bf16* aws = vtw + NT;

  dim3 gg(D_ / 128, M_ / 128), bb(256);
  gemm_bt<0, float, bf16><<<gg, bb, 0, stream>>>(x, Wq, bq, qws);
  gemm_bt<1, float, bf16><<<gg, bb, 0, stream>>>(x, Wk, bk, kws);
  gemm_bt<2, float, bf16><<<gg, bb, 0, stream>>>(x, Wv, bv, vtw);
  attn_fused<<<dim3(S_ / 64, B_ * H_), bb, 0, stream>>>(qws, kws, vtw, aws);
  gemm_bt<3, bf16, float><<<gg, bb, 0, stream>>>(aws, Wo, bo, out);
}